// Round 6
// baseline (498.943 us; speedup 1.0000x reference)
//
#include <hip/hip_runtime.h>
#include <math.h>

// Problem constants: B=4, H=8, L=512, HD=64, D=512, RHO=0.1
// Workspace (floats):
//   Q   : 1M   [BH][512][64]   (QKV base; later reused as Of [B][L][512])
//   Kt  : 1M
//   V   : 1M
//   S   : 8M   [BH][512][512]  (scores -> later J -> softmax'd P)
//   Am  : 8M   (adjacency -> A_hat in place)
//   T   : 8M   (A_hat@S temp)
//   R   : 16K  (row inv-sqrt degrees)

typedef __attribute__((ext_vector_type(8))) short short8v;
typedef __attribute__((ext_vector_type(4))) float f32x4;

// ---------------------------------------------------------------------------
// bf16 split helper: pack 8 fp32 -> hi/lo bf16x8 (truncation split)
// ---------------------------------------------------------------------------
__device__ __forceinline__ void split8(const float* v, unsigned* hi, unsigned* lo)
{
    #pragma unroll
    for (int q = 0; q < 4; ++q) {
        const unsigned b0 = __float_as_uint(v[2 * q])     & 0xFFFF0000u;
        const unsigned b1 = __float_as_uint(v[2 * q + 1]) & 0xFFFF0000u;
        const float d0 = v[2 * q]     - __uint_as_float(b0);
        const float d1 = v[2 * q + 1] - __uint_as_float(b1);
        hi[q] = (b0 >> 16) | b1;
        lo[q] = (__float_as_uint(d0) >> 16) | (__float_as_uint(d1) & 0xFFFF0000u);
    }
}

// ---------------------------------------------------------------------------
// Split-bf16 MFMA GEMM. 128x128 tile, 256 threads (4 waves 2x2), K-step 32.
// BT=0: C = A @ B; BT=1: C = A @ B^T. acc = Ahi*Bhi + Ahi*Blo + Alo*Bhi.
// ---------------------------------------------------------------------------
template<int BT>
__global__ __launch_bounds__(256)
void gemm_mfma(const float* __restrict__ Ap, const float* __restrict__ Bp,
               float* __restrict__ Cp, int K, int lda, int ldb, int ldc,
               long sA, long sB, long sC, float scale)
{
    const float* __restrict__ A = Ap + (long)blockIdx.z * sA;
    const float* __restrict__ B = Bp + (long)blockIdx.z * sB;
    float* __restrict__ C = Cp + (long)blockIdx.z * sC;
    const int m0 = blockIdx.y << 7, n0 = blockIdx.x << 7;

    __shared__ short Ah[128 * 32], Al[128 * 32], Bh[128 * 32], Bl[128 * 32];

    const int tid = threadIdx.x;
    const int lane = tid & 63, wv = tid >> 6;
    const int wr = wv >> 1, wc = wv & 1;

    f32x4 acc[4][4] = {};

    for (int k0 = 0; k0 < K; k0 += 32) {
        {
            const int row = tid >> 1;
            const int swz = (row & 3) ^ ((row >> 2) & 3);
            #pragma unroll
            for (int gg = 0; gg < 2; ++gg) {
                const int g = ((tid & 1) << 1) + gg;
                const float* src = A + (long)(m0 + row) * lda + k0 + (g << 3);
                float v[8];
                *(float4*)&v[0] = *(const float4*)src;
                *(float4*)&v[4] = *(const float4*)(src + 4);
                unsigned hi[4], lo[4];
                split8(v, hi, lo);
                const int off = row * 32 + ((g ^ swz) << 3);
                *(uint4*)&Ah[off] = *(uint4*)hi;
                *(uint4*)&Al[off] = *(uint4*)lo;
            }
        }
        if (BT) {
            const int row = tid >> 1;
            const int swz = (row & 3) ^ ((row >> 2) & 3);
            #pragma unroll
            for (int gg = 0; gg < 2; ++gg) {
                const int g = ((tid & 1) << 1) + gg;
                const float* src = B + (long)(n0 + row) * ldb + k0 + (g << 3);
                float v[8];
                *(float4*)&v[0] = *(const float4*)src;
                *(float4*)&v[4] = *(const float4*)(src + 4);
                unsigned hi[4], lo[4];
                split8(v, hi, lo);
                const int off = row * 32 + ((g ^ swz) << 3);
                *(uint4*)&Bh[off] = *(uint4*)hi;
                *(uint4*)&Bl[off] = *(uint4*)lo;
            }
        } else {
            const int n = tid & 127;
            const int swz = (n & 3) ^ ((n >> 2) & 3);
            #pragma unroll
            for (int gg = 0; gg < 2; ++gg) {
                const int g = ((tid >> 7) << 1) + gg;
                float v[8];
                #pragma unroll
                for (int e = 0; e < 8; ++e)
                    v[e] = B[(long)(k0 + (g << 3) + e) * ldb + n0 + n];
                unsigned hi[4], lo[4];
                split8(v, hi, lo);
                const int off = n * 32 + ((g ^ swz) << 3);
                *(uint4*)&Bh[off] = *(uint4*)hi;
                *(uint4*)&Bl[off] = *(uint4*)lo;
            }
        }
        __syncthreads();

        {
            const int r = lane & 15, g = lane >> 4;
            const int lswz = (r & 3) ^ ((r >> 2) & 3);
            const int gslot = ((g ^ lswz) << 3);
            const int abase = ((wr << 6) + r) * 32 + gslot;
            const int bbase = ((wc << 6) + r) * 32 + gslot;
            short8v afh[4], afl[4], bfh[4], bfl[4];
            #pragma unroll
            for (int f = 0; f < 4; ++f) {
                afh[f] = *(short8v*)&Ah[abase + f * 512];
                afl[f] = *(short8v*)&Al[abase + f * 512];
                bfh[f] = *(short8v*)&Bh[bbase + f * 512];
                bfl[f] = *(short8v*)&Bl[bbase + f * 512];
            }
            #pragma unroll
            for (int fi = 0; fi < 4; ++fi)
                #pragma unroll
                for (int fj = 0; fj < 4; ++fj) {
                    acc[fi][fj] = __builtin_amdgcn_mfma_f32_16x16x32_bf16(
                        afh[fi], bfh[fj], acc[fi][fj], 0, 0, 0);
                    acc[fi][fj] = __builtin_amdgcn_mfma_f32_16x16x32_bf16(
                        afh[fi], bfl[fj], acc[fi][fj], 0, 0, 0);
                    acc[fi][fj] = __builtin_amdgcn_mfma_f32_16x16x32_bf16(
                        afl[fi], bfh[fj], acc[fi][fj], 0, 0, 0);
                }
        }
        __syncthreads();
    }

    // C/D layout: col = lane&15, row = (lane>>4)*4 + reg  [m89/m91]
    const int r = lane & 15, g = lane >> 4;
    #pragma unroll
    for (int fi = 0; fi < 4; ++fi) {
        const int gr0 = m0 + (wr << 6) + fi * 16 + g * 4;
        #pragma unroll
        for (int fj = 0; fj < 4; ++fj) {
            const int gc = n0 + (wc << 6) + fj * 16 + r;
            #pragma unroll
            for (int qq = 0; qq < 4; ++qq)
                C[(long)(gr0 + qq) * ldc + gc] = acc[fi][fj][qq] * scale;
        }
    }
}

// ---------------------------------------------------------------------------
// Fused QKV projection via split-bf16 MFMA: x[2048x512] @ {Wq|Wk|Wv}[512x512]
// -> QKV [3][BH][512][64]. Grid (12, 16).
// ---------------------------------------------------------------------------
__global__ __launch_bounds__(256)
void gemm_qkv_mfma(const float* __restrict__ x, const float* __restrict__ Wq,
                   const float* __restrict__ Wk, const float* __restrict__ Wv,
                   float* __restrict__ QKV)
{
    const int m0 = blockIdx.y << 7;
    const int ng = blockIdx.x << 7;
    const float* __restrict__ W = (ng < 512) ? Wq : (ng < 1024) ? Wk : Wv;
    const int n0 = ng & 511;
    float* __restrict__ C = QKV + (long)(ng >> 9) * (1 << 20);

    __shared__ short Ah[128 * 32], Al[128 * 32], Bh[128 * 32], Bl[128 * 32];

    const int tid = threadIdx.x;
    const int lane = tid & 63, wv = tid >> 6;
    const int wr = wv >> 1, wc = wv & 1;

    f32x4 acc[4][4] = {};

    for (int k0 = 0; k0 < 512; k0 += 32) {
        {
            const int row = tid >> 1;
            const int swz = (row & 3) ^ ((row >> 2) & 3);
            #pragma unroll
            for (int gg = 0; gg < 2; ++gg) {
                const int g = ((tid & 1) << 1) + gg;
                const float* src = x + (long)(m0 + row) * 512 + k0 + (g << 3);
                float v[8];
                *(float4*)&v[0] = *(const float4*)src;
                *(float4*)&v[4] = *(const float4*)(src + 4);
                unsigned hi[4], lo[4];
                split8(v, hi, lo);
                const int off = row * 32 + ((g ^ swz) << 3);
                *(uint4*)&Ah[off] = *(uint4*)hi;
                *(uint4*)&Al[off] = *(uint4*)lo;
            }
        }
        {
            const int n = tid & 127;
            const int swz = (n & 3) ^ ((n >> 2) & 3);
            #pragma unroll
            for (int gg = 0; gg < 2; ++gg) {
                const int g = ((tid >> 7) << 1) + gg;
                float v[8];
                #pragma unroll
                for (int e = 0; e < 8; ++e)
                    v[e] = W[(long)(k0 + (g << 3) + e) * 512 + n0 + n];
                unsigned hi[4], lo[4];
                split8(v, hi, lo);
                const int off = n * 32 + ((g ^ swz) << 3);
                *(uint4*)&Bh[off] = *(uint4*)hi;
                *(uint4*)&Bl[off] = *(uint4*)lo;
            }
        }
        __syncthreads();

        {
            const int r = lane & 15, g = lane >> 4;
            const int lswz = (r & 3) ^ ((r >> 2) & 3);
            const int gslot = ((g ^ lswz) << 3);
            const int abase = ((wr << 6) + r) * 32 + gslot;
            const int bbase = ((wc << 6) + r) * 32 + gslot;
            short8v afh[4], afl[4], bfh[4], bfl[4];
            #pragma unroll
            for (int f = 0; f < 4; ++f) {
                afh[f] = *(short8v*)&Ah[abase + f * 512];
                afl[f] = *(short8v*)&Al[abase + f * 512];
                bfh[f] = *(short8v*)&Bh[bbase + f * 512];
                bfl[f] = *(short8v*)&Bl[bbase + f * 512];
            }
            #pragma unroll
            for (int fi = 0; fi < 4; ++fi)
                #pragma unroll
                for (int fj = 0; fj < 4; ++fj) {
                    acc[fi][fj] = __builtin_amdgcn_mfma_f32_16x16x32_bf16(
                        afh[fi], bfh[fj], acc[fi][fj], 0, 0, 0);
                    acc[fi][fj] = __builtin_amdgcn_mfma_f32_16x16x32_bf16(
                        afh[fi], bfl[fj], acc[fi][fj], 0, 0, 0);
                    acc[fi][fj] = __builtin_amdgcn_mfma_f32_16x16x32_bf16(
                        afl[fi], bfh[fj], acc[fi][fj], 0, 0, 0);
                }
        }
        __syncthreads();
    }

    const int r = lane & 15, g = lane >> 4;
    #pragma unroll
    for (int fi = 0; fi < 4; ++fi) {
        const int gr0 = m0 + (wr << 6) + fi * 16 + g * 4;
        #pragma unroll
        for (int fj = 0; fj < 4; ++fj) {
            const int nl = n0 + (wc << 6) + fj * 16 + r;
            const int h = nl >> 6, d = nl & 63;
            #pragma unroll
            for (int qq = 0; qq < 4; ++qq) {
                const int m = gr0 + qq;
                const int b = m >> 9, l = m & 511;
                C[((long)((b * 8 + h) * 512 + l)) * 64 + d] = acc[fi][fj][qq];
            }
        }
    }
}

// ---------------------------------------------------------------------------
// Adjacency v5: A[i,k] = 2^-15 * sum_j (p = S_ij*S_kj) if p > 0.1*64, diag 0.
// 64x64 tile, upper-tri tile pairs (36), mirrored write. 4 waves, each wave
// privately sums 128 j's (2 chunks/iter, A/B reg buffers, global loads issued
// a chunk ahead; lgkm-only drain so loads stay in flight under compute).
// 3-phase LDS tree reduce combines wave partials; wave 0 finalizes.
// ---------------------------------------------------------------------------
__global__ __launch_bounds__(256)
void adj_kernel(const float* __restrict__ S, float* __restrict__ A)
{
    const int bh = blockIdx.y;
    const float* __restrict__ Sh = S + (long)bh * 262144;
    float* __restrict__ Ah = A + (long)bh * 262144;

    int ti = 0, rem = blockIdx.x;
    while (rem >= 8 - ti) { rem -= 8 - ti; ++ti; }
    const int tk = ti + rem;
    const int i0 = ti << 6, k0 = tk << 6;

    __shared__ float smem[8704];        // 34816 B

    const int tid  = threadIdx.x;
    const int lane = tid & 63;
    const int wv   = tid >> 6;
    const int ly8  = (lane >> 3) << 3;
    const int lx8  = (lane & 7) << 3;
    const int r4   = lane >> 2;          // 0..15
    const int q    = lane & 3;           // 0..3

    float (*stgL)[68] = (float(*)[68])&smem[wv * 2176];
    float (*stgR)[68] = (float(*)[68])&smem[wv * 2176 + 1088];

    const float RHO64 = 0.1f * 64.0f;

    float acc[8][8] = {};
    const int jw = wv << 7;              // this wave's j base

    float4 la[4], ra[4], lb[4], rb[4];

    // prologue: chunk 0 -> A regs
    #pragma unroll
    for (int p = 0; p < 4; ++p) {
        la[p] = *(const float4*)(Sh + (long)(i0 + r4 + (p << 4)) * 512 + jw + (q << 2));
        ra[p] = *(const float4*)(Sh + (long)(k0 + r4 + (p << 4)) * 512 + jw + (q << 2));
    }

    for (int cc = 0; cc < 4; ++cc) {
        // ---- chunk 2cc (A regs): prefetch 2cc+1 into B, write A, compute ----
        {
            const int j1 = jw + ((2 * cc + 1) << 4);
            #pragma unroll
            for (int p = 0; p < 4; ++p) {
                lb[p] = *(const float4*)(Sh + (long)(i0 + r4 + (p << 4)) * 512 + j1 + (q << 2));
                rb[p] = *(const float4*)(Sh + (long)(k0 + r4 + (p << 4)) * 512 + j1 + (q << 2));
            }
            #pragma unroll
            for (int p = 0; p < 4; ++p) {
                const int row = r4 + (p << 4);
                stgL[(q << 2) + 0][row] = la[p].x;
                stgL[(q << 2) + 1][row] = la[p].y;
                stgL[(q << 2) + 2][row] = la[p].z;
                stgL[(q << 2) + 3][row] = la[p].w;
                stgR[(q << 2) + 0][row] = ra[p].x;
                stgR[(q << 2) + 1][row] = ra[p].y;
                stgR[(q << 2) + 2][row] = ra[p].z;
                stgR[(q << 2) + 3][row] = ra[p].w;
            }
            asm volatile("s_waitcnt lgkmcnt(0)" ::: "memory");
            __builtin_amdgcn_sched_barrier(0);
            #pragma unroll 4
            for (int jj = 0; jj < 16; ++jj) {
                float a[8], b[8];
                *(float4*)&a[0] = *(const float4*)&stgL[jj][ly8];
                *(float4*)&a[4] = *(const float4*)&stgL[jj][ly8 + 4];
                *(float4*)&b[0] = *(const float4*)&stgR[jj][lx8];
                *(float4*)&b[4] = *(const float4*)&stgR[jj][lx8 + 4];
                #pragma unroll
                for (int i = 0; i < 8; ++i)
                    #pragma unroll
                    for (int j = 0; j < 8; ++j) {
                        const float u = a[i] * b[j];
                        if (u > RHO64) acc[i][j] += u;
                    }
            }
        }
        // ---- chunk 2cc+1 (B regs): prefetch 2cc+2 into A, write B, compute ----
        {
            if (cc < 3) {
                const int j2 = jw + ((2 * cc + 2) << 4);
                #pragma unroll
                for (int p = 0; p < 4; ++p) {
                    la[p] = *(const float4*)(Sh + (long)(i0 + r4 + (p << 4)) * 512 + j2 + (q << 2));
                    ra[p] = *(const float4*)(Sh + (long)(k0 + r4 + (p << 4)) * 512 + j2 + (q << 2));
                }
            }
            #pragma unroll
            for (int p = 0; p < 4; ++p) {
                const int row = r4 + (p << 4);
                stgL[(q << 2) + 0][row] = lb[p].x;
                stgL[(q << 2) + 1][row] = lb[p].y;
                stgL[(q << 2) + 2][row] = lb[p].z;
                stgL[(q << 2) + 3][row] = lb[p].w;
                stgR[(q << 2) + 0][row] = rb[p].x;
                stgR[(q << 2) + 1][row] = rb[p].y;
                stgR[(q << 2) + 2][row] = rb[p].z;
                stgR[(q << 2) + 3][row] = rb[p].w;
            }
            asm volatile("s_waitcnt lgkmcnt(0)" ::: "memory");
            __builtin_amdgcn_sched_barrier(0);
            #pragma unroll 4
            for (int jj = 0; jj < 16; ++jj) {
                float a[8], b[8];
                *(float4*)&a[0] = *(const float4*)&stgL[jj][ly8];
                *(float4*)&a[4] = *(const float4*)&stgL[jj][ly8 + 4];
                *(float4*)&b[0] = *(const float4*)&stgR[jj][lx8];
                *(float4*)&b[4] = *(const float4*)&stgR[jj][lx8 + 4];
                #pragma unroll
                for (int i = 0; i < 8; ++i)
                    #pragma unroll
                    for (int j = 0; j < 8; ++j) {
                        const float u = a[i] * b[j];
                        if (u > RHO64) acc[i][j] += u;
                    }
            }
        }
    }

    // ---- 3-phase reduce: (w0+w1) + (w3+w2), result in wave 0 ----
    float* red0 = &smem[0];
    float* red1 = &smem[4352];

    __syncthreads();
    if (wv == 1 || wv == 2) {
        float* dst = (wv == 1 ? red0 : red1) + lane * 68;
        #pragma unroll
        for (int i = 0; i < 8; ++i) {
            *(float4*)(dst + i * 8)     = *(float4*)&acc[i][0];
            *(float4*)(dst + i * 8 + 4) = *(float4*)&acc[i][4];
        }
    }
    __syncthreads();
    if (wv == 0 || wv == 3) {
        const float* src = (wv == 0 ? red0 : red1) + lane * 68;
        #pragma unroll
        for (int i = 0; i < 8; ++i) {
            float4 p0 = *(const float4*)(src + i * 8);
            float4 p1 = *(const float4*)(src + i * 8 + 4);
            acc[i][0] += p0.x; acc[i][1] += p0.y; acc[i][2] += p0.z; acc[i][3] += p0.w;
            acc[i][4] += p1.x; acc[i][5] += p1.y; acc[i][6] += p1.z; acc[i][7] += p1.w;
        }
    }
    __syncthreads();
    if (wv == 3) {
        float* dst = red0 + lane * 68;
        #pragma unroll
        for (int i = 0; i < 8; ++i) {
            *(float4*)(dst + i * 8)     = *(float4*)&acc[i][0];
            *(float4*)(dst + i * 8 + 4) = *(float4*)&acc[i][4];
        }
    }
    __syncthreads();
    if (wv == 0) {
        const float* src = red0 + lane * 68;
        const float SC = 1.0f / 32768.0f;    // 2^-15 exact
        float f[8][8];
        #pragma unroll
        for (int i = 0; i < 8; ++i) {
            float4 p0 = *(const float4*)(src + i * 8);
            float4 p1 = *(const float4*)(src + i * 8 + 4);
            f[i][0] = (acc[i][0] + p0.x) * SC;
            f[i][1] = (acc[i][1] + p0.y) * SC;
            f[i][2] = (acc[i][2] + p0.z) * SC;
            f[i][3] = (acc[i][3] + p0.w) * SC;
            f[i][4] = (acc[i][4] + p1.x) * SC;
            f[i][5] = (acc[i][5] + p1.y) * SC;
            f[i][6] = (acc[i][6] + p1.z) * SC;
            f[i][7] = (acc[i][7] + p1.w) * SC;
        }
        if (ti == tk) {
            #pragma unroll
            for (int i = 0; i < 8; ++i)
                #pragma unroll
                for (int j = 0; j < 8; ++j)
                    if (ly8 + i == lx8 + j) f[i][j] = 0.0f;
        }
        #pragma unroll
        for (int i = 0; i < 8; ++i) {
            float* dst = Ah + (long)(i0 + ly8 + i) * 512 + k0 + lx8;
            *(float4*)dst       = make_float4(f[i][0], f[i][1], f[i][2], f[i][3]);
            *(float4*)(dst + 4) = make_float4(f[i][4], f[i][5], f[i][6], f[i][7]);
        }
        if (ti != tk) {
            #pragma unroll
            for (int j = 0; j < 8; ++j) {
                float* dst = Ah + (long)(k0 + lx8 + j) * 512 + i0 + ly8;
                *(float4*)dst       = make_float4(f[0][j], f[1][j], f[2][j], f[3][j]);
                *(float4*)(dst + 4) = make_float4(f[4][j], f[5][j], f[6][j], f[7][j]);
            }
        }
    }
}

// ---------------------------------------------------------------------------
// Row degree: R[row] = 1/sqrt(clip(1 + sum_k A[row,k], 1e-6))
// ---------------------------------------------------------------------------
__global__ __launch_bounds__(256)
void rowsum_kernel(const float* __restrict__ A, float* __restrict__ R)
{
    const int row = (blockIdx.x << 2) + (threadIdx.x >> 6);
    const int lane = threadIdx.x & 63;
    const float* p = A + (long)row * 512;
    float s = 0.0f;
    #pragma unroll
    for (int t = 0; t < 8; ++t) s += p[lane + (t << 6)];
    #pragma unroll
    for (int off = 32; off; off >>= 1) s += __shfl_xor(s, off, 64);
    if (lane == 0) R[row] = 1.0f / sqrtf(fmaxf(1.0f + s, 1e-6f));
}

// ---------------------------------------------------------------------------
// A_hat[i,k] = R[i]*R[k]*(A[i,k] + (i==k)) in place
// ---------------------------------------------------------------------------
__global__ __launch_bounds__(256)
void ahat_kernel(float* __restrict__ A, const float* __restrict__ R)
{
    const long i4 = ((long)blockIdx.x * 256 + threadIdx.x) << 2;
    const long off = i4 & 262143;
    const long bh = i4 >> 18;
    const int i = (int)(off >> 9);
    const int k = (int)(off & 511);
    const float ri = R[(bh << 9) + i];
    const float* Rk = R + (bh << 9) + k;
    float4 v = *(float4*)(A + i4);
    v.x = ri * Rk[0] * (v.x + ((k + 0) == i ? 1.0f : 0.0f));
    v.y = ri * Rk[1] * (v.y + ((k + 1) == i ? 1.0f : 0.0f));
    v.z = ri * Rk[2] * (v.z + ((k + 2) == i ? 1.0f : 0.0f));
    v.w = ri * Rk[3] * (v.w + ((k + 3) == i ? 1.0f : 0.0f));
    *(float4*)(A + i4) = v;
}

// ---------------------------------------------------------------------------
// Row softmax over 512, in place. Wave per row, 4 rows/block, no barriers.
// ---------------------------------------------------------------------------
__global__ __launch_bounds__(256)
void softmax_kernel(float* __restrict__ P)
{
    const int row = (blockIdx.x << 2) + (threadIdx.x >> 6);
    const int lane = threadIdx.x & 63;
    float* p = P + (long)row * 512 + (lane << 3);
    float4 v0 = *(float4*)p;
    float4 v1 = *(float4*)(p + 4);
    float mx = fmaxf(fmaxf(fmaxf(v0.x, v0.y), fmaxf(v0.z, v0.w)),
                     fmaxf(fmaxf(v1.x, v1.y), fmaxf(v1.z, v1.w)));
    #pragma unroll
    for (int off = 32; off; off >>= 1) mx = fmaxf(mx, __shfl_xor(mx, off, 64));
    float e[8];
    e[0] = __expf(v0.x - mx); e[1] = __expf(v0.y - mx);
    e[2] = __expf(v0.z - mx); e[3] = __expf(v0.w - mx);
    e[4] = __expf(v1.x - mx); e[5] = __expf(v1.y - mx);
    e[6] = __expf(v1.z - mx); e[7] = __expf(v1.w - mx);
    float s = (((e[0] + e[1]) + (e[2] + e[3])) + ((e[4] + e[5]) + (e[6] + e[7])));
    #pragma unroll
    for (int off = 32; off; off >>= 1) s += __shfl_xor(s, off, 64);
    const float inv = 1.0f / s;
    *(float4*)p       = make_float4(e[0] * inv, e[1] * inv, e[2] * inv, e[3] * inv);
    *(float4*)(p + 4) = make_float4(e[4] * inv, e[5] * inv, e[6] * inv, e[7] * inv);
}

// ---------------------------------------------------------------------------
// O = P @ V per head via split-bf16 MFMA, writing DIRECTLY to Of layout
// [B][L][H*HD]. M=512, N=64, K=512. 128x64 tile, 4 waves stacked on M.
// Grid (1, 4, 32).
// ---------------------------------------------------------------------------
__global__ __launch_bounds__(256)
void gemm_pv_mfma(const float* __restrict__ P, const float* __restrict__ V,
                  float* __restrict__ Of)
{
    const int bh = blockIdx.z;
    const float* __restrict__ Pp = P + (long)bh * 262144;
    const float* __restrict__ Vp = V + (long)bh * 32768;
    const int bb = bh >> 3, hh = bh & 7;
    const int m0 = blockIdx.y << 7;

    __shared__ short Ph[128 * 32], Pl[128 * 32], Vh[64 * 32], Vl[64 * 32];

    const int tid = threadIdx.x;
    const int lane = tid & 63, wv = tid >> 6;

    f32x4 acc[2][4] = {};

    for (int k0 = 0; k0 < 512; k0 += 32) {
        {
            const int row = tid >> 1;
            const int swz = (row & 3) ^ ((row >> 2) & 3);
            #pragma unroll
            for (int gg = 0; gg < 2; ++gg) {
                const int g = ((tid & 1) << 1) + gg;
                const float* src = Pp + (long)(m0 + row) * 512 + k0 + (g << 3);
                float v[8];
                *(float4*)&v[0] = *(const float4*)src;
                *(float4*)&v[4] = *(const float4*)(src + 4);
                unsigned hi[4], lo[4];
                split8(v, hi, lo);
                const int off = row * 32 + ((g ^ swz) << 3);
                *(uint4*)&Ph[off] = *(uint4*)hi;
                *(uint4*)&Pl[off] = *(uint4*)lo;
            }
        }
        {
            const int n = tid & 63, g = tid >> 6;
            const int swz = (n & 3) ^ ((n >> 2) & 3);
            float v[8];
            #pragma unroll
            for (int e = 0; e < 8; ++e)
                v[e] = Vp[(long)(k0 + (g << 3) + e) * 64 + n];
            unsigned hi[4], lo[4];
            split8(v, hi, lo);
            const int off = n * 32 + ((g ^ swz) << 3);
            *(uint4*)&Vh[off] = *(uint4*)hi;
            *(uint4*)&Vl[off] = *(uint4*)lo;
        }
        __syncthreads();

        {
            const int r = lane & 15, g = lane >> 4;
            const int lswz = (r & 3) ^ ((r >> 2) & 3);
            const int gslot = ((g ^ lswz) << 3);
            short8v afh[2], afl[2], bfh[4], bfl[4];
            #pragma unroll
            for (int fi = 0; fi < 2; ++fi) {
                const int abase = ((wv << 5) + (fi << 4) + r) * 32 + gslot;
                afh[fi] = *(short8v*)&Ph[abase];
                afl[fi] = *(short8v*)&Pl[abase];
            }
            #pragma unroll
            for (int fj = 0; fj < 4; ++fj) {
                const int bbase = ((fj << 4) + r) * 32 + gslot;
                bfh[fj] = *(short8v*)&Vh[bbase];
                bfl[fj] = *(short8v*)&Vl[bbase];
            }
            #pragma unroll
            for (int fi = 0; fi < 2; ++fi)
                #pragma unroll
                for (int fj = 0; fj < 4; ++fj) {
                    acc[fi][fj] = __builtin_amdgcn_mfma_f32_16x16x32_bf16(
                        afh[fi], bfh[fj], acc[fi][fj], 0, 0, 0);
                    acc[fi][fj] = __builtin_amdgcn_mfma_f32_16x16x32_bf16(
                        afh[fi], bfl[fj], acc[fi][fj], 0, 0, 0);
                    acc[fi][fj] = __builtin_amdgcn_mfma_f32_16x16x32_bf16(
                        afl[fi], bfh[fj], acc[fi][fj], 0, 0, 0);
                }
        }
        __syncthreads();
    }

    // write to Of [B][L][512]: row l = m, col = h*64 + (fj*16 + r)
    const int r = lane & 15, g = lane >> 4;
    #pragma unroll
    for (int fi = 0; fi < 2; ++fi) {
        const int l0 = m0 + (wv << 5) + fi * 16 + g * 4;
        #pragma unroll
        for (int fj = 0; fj < 4; ++fj) {
            const int d = fj * 16 + r;
            #pragma unroll
            for (int qq = 0; qq < 4; ++qq)
                Of[((long)((bb << 9) + l0 + qq) << 9) + (hh << 6) + d] = acc[fi][fj][qq];
        }
    }
}

// ---------------------------------------------------------------------------
extern "C" void kernel_launch(void* const* d_in, const int* in_sizes, int n_in,
                              void* d_out, int out_size, void* d_ws, size_t ws_size,
                              hipStream_t stream)
{
    const float* x  = (const float*)d_in[0];
    const float* Wq = (const float*)d_in[1];
    const float* Wk = (const float*)d_in[2];
    const float* Wv = (const float*)d_in[3];
    const float* Wo = (const float*)d_in[4];
    float* out = (float*)d_out;

    float* ws = (float*)d_ws;
    float* Q  = ws;                       // 1M floats (QKV base; later Of)
    float* Kt = Q  + (1u << 20);          // 1M
    float* V  = Kt + (1u << 20);          // 1M
    float* S  = V  + (1u << 20);          // 8M
    float* Am = S  + (8u << 20);          // 8M (adjacency -> A_hat)
    float* T  = Am + (8u << 20);          // 8M (A_hat@S temp)
    float* R  = T  + (8u << 20);          // 16K

    dim3 blk(256);

    // 1) fused QKV projections (split-bf16 MFMA)
    gemm_qkv_mfma<<<dim3(12, 16, 1), blk, 0, stream>>>(x, Wq, Wk, Wv, Q);

    // 2) S = Q K^T per head (MFMA, K=64)
    gemm_mfma<1><<<dim3(4, 4, 32), blk, 0, stream>>>(Q, Kt, S, 64, 64, 64, 512,
                                                     32768, 32768, 262144, 1.0f);

    // 3) adjacency (4 waves, pipelined chunks, mirrored symmetric write)
    adj_kernel<<<dim3(36, 32), blk, 0, stream>>>(S, Am);

    // 4) row degrees -> R
    rowsum_kernel<<<dim3(4096), blk, 0, stream>>>(Am, R);

    // 5) A_hat in place
    ahat_kernel<<<dim3(8192), blk, 0, stream>>>(Am, R);

    // 6) T = A_hat @ S (MFMA)
    gemm_mfma<0><<<dim3(4, 4, 32), blk, 0, stream>>>(Am, S, T, 512, 512, 512, 512,
                                                     262144, 262144, 262144, 1.0f);

    // 7) J = T @ A_hat^T / 8 -> S (MFMA)
    gemm_mfma<1><<<dim3(4, 4, 32), blk, 0, stream>>>(T, Am, S, 512, 512, 512, 512,
                                                     262144, 262144, 262144, 0.125f);

    // 8) softmax rows of J (wave per row)
    softmax_kernel<<<dim3(4096), blk, 0, stream>>>(S);

    // 9) O = P @ V -> Of directly (reuse Q buffer)
    gemm_pv_mfma<<<dim3(1, 4, 32), blk, 0, stream>>>(S, V, Q);

    // 10) out = Of @ Wo (MFMA)
    gemm_mfma<0><<<dim3(4, 16, 1), blk, 0, stream>>>(Q, Wo, out, 512, 512, 512, 512,
                                                     0, 0, 0, 1.0f);
}